// Round 4
// baseline (755.184 us; speedup 1.0000x reference)
//
#include <hip/hip_runtime.h>
#include <hip/hip_bf16.h>
#include <cstdint>
#include <cstddef>

typedef __bf16 bf16;
typedef __bf16 bf16x8 __attribute__((ext_vector_type(8)));
typedef __bf16 bf16x4 __attribute__((ext_vector_type(4)));
typedef float  f32x4  __attribute__((ext_vector_type(4)));

typedef __attribute__((address_space(1))) void gvoid_t;
typedef __attribute__((address_space(3))) void lvoid_t;

// async global->LDS, 16B per lane; LDS dest must be wave-uniform base (HW adds lane*16)
#define GLD_LDS16(g, l) __builtin_amdgcn_global_load_lds( \
    (gvoid_t*)(uintptr_t)(g), (lvoid_t*)(uint32_t)(uintptr_t)(l), 16, 0, 0)

#define SBAR() __builtin_amdgcn_s_barrier()
#define WAIT_VM0() asm volatile("s_waitcnt vmcnt(0)" ::: "memory")

// ---------------------------------------------------------------------------
// Weight transpose + f32->bf16 cast:  in [R][C] f32  ->  out [C][R] bf16
// ---------------------------------------------------------------------------
__global__ __launch_bounds__(256) void transpose_cast(
    const float* __restrict__ in, bf16* __restrict__ out, int R, int C)
{
  __shared__ float tile[32][33];
  const int bx = blockIdx.x;   // C/32
  const int by = blockIdx.y;   // R/32
  const int tx = threadIdx.x;  // 0..31
  const int ty = threadIdx.y;  // 0..7
#pragma unroll
  for (int i = 0; i < 32; i += 8)
    tile[ty + i][tx] = in[(size_t)(by * 32 + ty + i) * C + bx * 32 + tx];
  __syncthreads();
#pragma unroll
  for (int i = 0; i < 32; i += 8)
    out[(size_t)(bx * 32 + ty + i) * R + by * 32 + tx] = (bf16)tile[tx][ty + i];
}

// ---------------------------------------------------------------------------
// LayerNorm over H=1024, f32 in -> bf16 out. One block (256 thr) per row.
// ---------------------------------------------------------------------------
__global__ __launch_bounds__(256) void ln_row(
    const float* __restrict__ x, const float* __restrict__ w,
    const float* __restrict__ b, bf16* __restrict__ out)
{
  const int row = blockIdx.x;
  const int tid = threadIdx.x;
  const float4 v = ((const float4*)(x + (size_t)row * 1024))[tid];
  float s  = v.x + v.y + v.z + v.w;
  float ss = v.x * v.x + v.y * v.y + v.z * v.z + v.w * v.w;
#pragma unroll
  for (int off = 32; off > 0; off >>= 1) {
    s  += __shfl_down(s, off);
    ss += __shfl_down(ss, off);
  }
  __shared__ float red[8];
  const int wid = tid >> 6, lane = tid & 63;
  if (lane == 0) { red[wid] = s; red[4 + wid] = ss; }
  __syncthreads();
  s  = red[0] + red[1] + red[2] + red[3];
  ss = red[4] + red[5] + red[6] + red[7];
  const float mu   = s * (1.f / 1024.f);
  const float var  = ss * (1.f / 1024.f) - mu * mu;
  const float rstd = rsqrtf(var + 1e-5f);
  const float4 wv = ((const float4*)w)[tid];
  const float4 bv = ((const float4*)b)[tid];
  bf16x4 ov;
  ov[0] = (bf16)((v.x - mu) * rstd * wv.x + bv.x);
  ov[1] = (bf16)((v.y - mu) * rstd * wv.y + bv.y);
  ov[2] = (bf16)((v.z - mu) * rstd * wv.z + bv.z);
  ov[3] = (bf16)((v.w - mu) * rstd * wv.w + bv.w);
  *(bf16x4*)(out + (size_t)row * 1024 + tid * 4) = ov;
}

// ---------------------------------------------------------------------------
// 128x128 GEMM, BK=64, 4 waves (2x2), 4x4 16x16x32 frags/wave.
// LDS 64KB (dbuf x {A,B} [128][64] bf16) -> 2 blocks/CU: cross-block overlap
// hides the per-tile vmcnt(0)+barrier drain (m97/m114 mechanism).
// 8-slot XOR swizzle (slot ^= row&7, 16B slots) on BOTH gld_lds source and
// ds_read -> 0 bank conflicts. Raw s_barrier (no compiler full-drain).
// EPI: 0 bias->bf16 | 1 bias->elu+1->bf16 | 2 bias+resid->f32 | 3 bias->gelu->bf16
// ---------------------------------------------------------------------------
template <int EPI>
__global__ __launch_bounds__(256, 2) void gemm128(
    const bf16* __restrict__ A, const bf16* __restrict__ BT,
    const float* __restrict__ bias, const float* __restrict__ resid,
    void* __restrict__ outp, int M, int N, int K, int nx)
{
  __shared__ __align__(16) char lds[65536];
  const int tid  = threadIdx.x;
  const int wid  = tid >> 6, lane = tid & 63;
  const int wr   = wid >> 1, wc = wid & 1;
  const int ln15 = lane & 15, lhi = lane >> 4;

  // chunked XCD swizzle + row-major logical tile order
  const int nwg = (int)gridDim.x;
  const int cpx = nwg >> 3;
  const int bid = (int)blockIdx.x;
  const int lg  = (bid & 7) * cpx + (bid >> 3);
  const int bx  = lg % nx, by = lg / nx;
  const int row0 = by << 7, col0 = bx << 7;

  // staging: 4 gld_lds per matrix per tile; issue i covers rows i*32+(tid>>3),
  // 16B slot (tid&7) in LDS holds global slot (tid&7)^(row&7).
  const int srow  = tid >> 3;                  // 0..31
  const int sslot = (tid & 7) ^ (srow & 7);
  const bf16* aS = A  + (size_t)(row0 + srow) * K + sslot * 8;
  const bf16* bS = BT + (size_t)(col0 + srow) * K + sslot * 8;
  const size_t rjump = (size_t)K << 5;         // +32 rows
  char* ldsW = lds + wid * 1024;               // per-wave linear dest base

  // swizzled read offsets (row&7 == ln15&7 for all frags: row steps are x16)
  const int rwA = (wr << 6) + ln15;
  const int rwB = (wc << 6) + ln15;
  const int s0  = lhi ^ (ln15 & 7);
  const int s1  = (4 + lhi) ^ (ln15 & 7);
  const int aOff0 = rwA * 128 + s0 * 16;
  const int aOff1 = rwA * 128 + s1 * 16;
  const int bOff0 = 32768 + rwB * 128 + s0 * 16;
  const int bOff1 = 32768 + rwB * 128 + s1 * 16;

  f32x4 acc[4][4] = {};
  const int nt = K >> 6;

#define STG(D, KT) do { \
    const bf16* ga_ = aS + (size_t)(KT) * 64; \
    const bf16* gb_ = bS + (size_t)(KT) * 64; \
    char* la_ = ldsW + (D) * 16384; \
    char* lb_ = la_ + 32768; \
    GLD_LDS16(ga_,             la_);         GLD_LDS16(gb_,             lb_); \
    GLD_LDS16(ga_ + rjump,     la_ + 4096);  GLD_LDS16(gb_ + rjump,     lb_ + 4096); \
    GLD_LDS16(ga_ + 2 * rjump, la_ + 8192);  GLD_LDS16(gb_ + 2 * rjump, lb_ + 8192); \
    GLD_LDS16(ga_ + 3 * rjump, la_ + 12288); GLD_LDS16(gb_ + 3 * rjump, lb_ + 12288); \
  } while (0)

  STG(0, 0);
  WAIT_VM0();
  SBAR();

  for (int kt = 0; kt < nt; ++kt) {
    const int d = kt & 1;
    const char* base = (const char*)lds + d * 16384;

    bf16x8 a0[4], b0[4], a1[4], b1[4];
#pragma unroll
    for (int m = 0; m < 4; ++m) a0[m] = *(const bf16x8*)(base + aOff0 + m * 2048);
#pragma unroll
    for (int n = 0; n < 4; ++n) b0[n] = *(const bf16x8*)(base + bOff0 + n * 2048);

    if (kt + 1 < nt) STG(d ^ 1, kt + 1);

#pragma unroll
    for (int m = 0; m < 4; ++m) a1[m] = *(const bf16x8*)(base + aOff1 + m * 2048);
#pragma unroll
    for (int n = 0; n < 4; ++n) b1[n] = *(const bf16x8*)(base + bOff1 + n * 2048);

    __builtin_amdgcn_s_setprio(1);
#pragma unroll
    for (int m = 0; m < 4; ++m)
#pragma unroll
      for (int n = 0; n < 4; ++n)
        acc[m][n] = __builtin_amdgcn_mfma_f32_16x16x32_bf16(a0[m], b0[n], acc[m][n], 0, 0, 0);
#pragma unroll
    for (int m = 0; m < 4; ++m)
#pragma unroll
      for (int n = 0; n < 4; ++n)
        acc[m][n] = __builtin_amdgcn_mfma_f32_16x16x32_bf16(a1[m], b1[n], acc[m][n], 0, 0, 0);
    __builtin_amdgcn_s_setprio(0);

    WAIT_VM0();   // t+1 loads issued a full tile ago; partner block hides residue
    SBAR();
  }
#undef STG

  // epilogue
  const int lr4 = lhi << 2;
#pragma unroll
  for (int m = 0; m < 4; ++m) {
#pragma unroll
    for (int n = 0; n < 4; ++n) {
      const int c_i = col0 + wc * 64 + n * 16 + ln15;
      const float bv = bias[c_i];
#pragma unroll
      for (int j = 0; j < 4; ++j) {
        const int r_i = row0 + wr * 64 + m * 16 + lr4 + j;
        const size_t idx = (size_t)r_i * N + c_i;
        float val = acc[m][n][j] + bv;
        if constexpr (EPI == 0) {
          ((bf16*)outp)[idx] = (bf16)val;
        } else if constexpr (EPI == 1) {
          ((bf16*)outp)[idx] = (bf16)(val > 0.f ? val + 1.f : __expf(val));
        } else if constexpr (EPI == 2) {
          ((float*)outp)[idx] = val + resid[idx];
        } else {
          const float u  = 0.7978845608028654f * (val + 0.044715f * val * val * val);
          const float th = 1.f - 2.f / (__expf(2.f * u) + 1.f);
          ((bf16*)outp)[idx] = (bf16)(0.5f * val * (1.f + th));
        }
      }
    }
  }
}

// ---------------------------------------------------------------------------
// kv partials: per (b,h) and 512-token chunk, kv[d][e] = sum_t kf[t,d]*v[t,e],
// ksum[d] = sum_t kf[t,d].  grid = 64 heads * 8 chunks.
// ---------------------------------------------------------------------------
__global__ __launch_bounds__(256) void kv_part_kernel(
    const bf16* __restrict__ kf, const bf16* __restrict__ v,
    float* __restrict__ kv_part, float* __restrict__ ksum_part)
{
  const int bh = blockIdx.x >> 3, ch = blockIdx.x & 7;
  const int b = bh >> 4, h = bh & 15;
  const int tid = threadIdx.x;
  const int e = tid & 63, dg = tid >> 6;
  const size_t grow0 = (size_t)b * 4096 + (size_t)ch * 512;
  const size_t cbase = (size_t)h * 64;
  __shared__ bf16 skf[8][64], sv[8][64];
  float accum[16];
#pragma unroll
  for (int i = 0; i < 16; ++i) accum[i] = 0.f;
  float ks = 0.f;
  const int tt = tid >> 5, cc = (tid & 31) << 1;
  for (int t0 = 0; t0 < 512; t0 += 8) {
    __syncthreads();
    const size_t base = (grow0 + t0 + tt) * 1024 + cbase + cc;
    *(uint32_t*)&skf[tt][cc] = *(const uint32_t*)(kf + base);
    *(uint32_t*)&sv[tt][cc]  = *(const uint32_t*)(v + base);
    __syncthreads();
#pragma unroll
    for (int q = 0; q < 8; ++q) {
      const float vv = (float)sv[q][e];
#pragma unroll
      for (int dd = 0; dd < 16; ++dd)
        accum[dd] += (float)skf[q][dg * 16 + dd] * vv;
    }
    if (tid < 64) {
#pragma unroll
      for (int q = 0; q < 8; ++q) ks += (float)skf[q][tid];
    }
  }
  float* op = kv_part + (size_t)blockIdx.x * 4096 + (size_t)(dg * 16) * 64 + e;
#pragma unroll
  for (int dd = 0; dd < 16; ++dd) op[dd * 64] = accum[dd];
  if (tid < 64) ksum_part[(size_t)blockIdx.x * 64 + tid] = ks;
}

__global__ __launch_bounds__(256) void kv_reduce(
    const float* __restrict__ kvp, const float* __restrict__ ksp,
    float* __restrict__ kvf, float* __restrict__ ksf)
{
  const int bh = blockIdx.x;
  const int tid = threadIdx.x;
  for (int i = tid; i < 4096; i += 256) {
    float s = 0.f;
#pragma unroll
    for (int ch = 0; ch < 8; ++ch) s += kvp[((size_t)bh * 8 + ch) * 4096 + i];
    kvf[(size_t)bh * 4096 + i] = s;
  }
  if (tid < 64) {
    float s = 0.f;
#pragma unroll
    for (int ch = 0; ch < 8; ++ch) s += ksp[((size_t)bh * 8 + ch) * 64 + tid];
    ksf[(size_t)bh * 64 + tid] = s;
  }
}

// ---------------------------------------------------------------------------
// attn out: out[t,e] = (qf[t,:].kv[:,e]) / (qf[t,:].ksum + 1e-6) -> bf16
// ---------------------------------------------------------------------------
__global__ __launch_bounds__(256) void attn_out_kernel(
    const bf16* __restrict__ qf, const float* __restrict__ kvf,
    const float* __restrict__ ksf, bf16* __restrict__ attn)
{
  const int bh = blockIdx.x >> 6, rb = blockIdx.x & 63;
  const int b = bh >> 4, h = bh & 15;
  const int tid = threadIdx.x;
  const int e = tid & 63, rbase = (tid >> 6) << 4;
  __shared__ __align__(16) bf16 sqf[64][64];
  __shared__ float sks[64];
  const size_t grow0 = (size_t)b * 4096 + (size_t)rb * 64;

  {
    const int rr = tid >> 2, c0 = (tid & 3) << 4;
    const bf16* src = qf + (grow0 + rr) * 1024 + h * 64 + c0;
    *(bf16x8*)&sqf[rr][c0]     = *(const bf16x8*)src;
    *(bf16x8*)&sqf[rr][c0 + 8] = *(const bf16x8*)(src + 8);
  }
  if (tid < 64) sks[tid] = ksf[(size_t)bh * 64 + tid];

  float kcol[64];
#pragma unroll
  for (int d = 0; d < 64; ++d) kcol[d] = kvf[(size_t)bh * 4096 + d * 64 + e];

  __syncthreads();

  for (int rr = 0; rr < 16; ++rr) {
    const int r = rbase + rr;
    bf16x8 q8[8];
#pragma unroll
    for (int i = 0; i < 8; ++i) q8[i] = *(const bf16x8*)&sqf[r][i * 8];
    float sk = 0.f, sv = 0.f;
#pragma unroll
    for (int i = 0; i < 8; ++i)
#pragma unroll
      for (int jj = 0; jj < 8; ++jj) {
        const float qd = (float)q8[i][jj];
        sk += qd * sks[i * 8 + jj];
        sv += qd * kcol[i * 8 + jj];
      }
    attn[(grow0 + r) * 1024 + h * 64 + e] = (bf16)(sv / (sk + 1e-6f));
  }
}

// ---------------------------------------------------------------------------
// launch
// ---------------------------------------------------------------------------
extern "C" void kernel_launch(void* const* d_in, const int* in_sizes, int n_in,
                              void* d_out, int out_size, void* d_ws, size_t ws_size,
                              hipStream_t stream)
{
  const float* x    = (const float*)d_in[0];
  const float* ln1w = (const float*)d_in[1];
  const float* ln1b = (const float*)d_in[2];
  const float* qw   = (const float*)d_in[3];
  const float* qb   = (const float*)d_in[4];
  const float* kw   = (const float*)d_in[5];
  const float* kb   = (const float*)d_in[6];
  const float* vw   = (const float*)d_in[7];
  const float* vb   = (const float*)d_in[8];
  const float* ow   = (const float*)d_in[9];
  const float* ob   = (const float*)d_in[10];
  const float* ln2w = (const float*)d_in[11];
  const float* ln2b = (const float*)d_in[12];
  const float* fcw  = (const float*)d_in[13];
  const float* fcb  = (const float*)d_in[14];
  const float* pjw  = (const float*)d_in[15];
  const float* pjb  = (const float*)d_in[16];
  float* out = (float*)d_out;
  char* ws = (char*)d_ws;

  constexpr size_t O_LNX  = 0;
  constexpr size_t O_QF   = 33554432;
  constexpr size_t O_KF   = 67108864;
  constexpr size_t O_V    = 100663296;
  constexpr size_t O_HMLP = 0;
  constexpr size_t O_KVP  = 134217728;
  constexpr size_t O_KSP  = 142606336;
  constexpr size_t O_KVF  = 142737408;
  constexpr size_t O_KSF  = 143785984;
  constexpr size_t O_ATTN = 143802368;
  constexpr size_t O_LN2  = 177356800;
  constexpr size_t O_WQ   = 210911232;
  constexpr size_t O_WK   = 213008384;
  constexpr size_t O_WV   = 215105536;
  constexpr size_t O_WO   = 217202688;
  constexpr size_t O_WFC  = 219299840;
  constexpr size_t O_WPJ  = 227688448;

  bf16* lnx  = (bf16*)(ws + O_LNX);
  bf16* qfb  = (bf16*)(ws + O_QF);
  bf16* kfb  = (bf16*)(ws + O_KF);
  bf16* vbuf = (bf16*)(ws + O_V);
  bf16* hmlp = (bf16*)(ws + O_HMLP);
  float* kvp = (float*)(ws + O_KVP);
  float* ksp = (float*)(ws + O_KSP);
  float* kvf = (float*)(ws + O_KVF);
  float* ksf = (float*)(ws + O_KSF);
  bf16* attn = (bf16*)(ws + O_ATTN);
  bf16* ln2h = (bf16*)(ws + O_LN2);
  bf16* wqT  = (bf16*)(ws + O_WQ);
  bf16* wkT  = (bf16*)(ws + O_WK);
  bf16* wvT  = (bf16*)(ws + O_WV);
  bf16* woT  = (bf16*)(ws + O_WO);
  bf16* wfcT = (bf16*)(ws + O_WFC);
  bf16* wpjT = (bf16*)(ws + O_WPJ);

  const dim3 tb(32, 8);
  transpose_cast<<<dim3(32, 32),  tb, 0, stream>>>(qw,  wqT, 1024, 1024);
  transpose_cast<<<dim3(32, 32),  tb, 0, stream>>>(kw,  wkT, 1024, 1024);
  transpose_cast<<<dim3(32, 32),  tb, 0, stream>>>(vw,  wvT, 1024, 1024);
  transpose_cast<<<dim3(32, 32),  tb, 0, stream>>>(ow,  woT, 1024, 1024);
  transpose_cast<<<dim3(128, 32), tb, 0, stream>>>(fcw, wfcT, 1024, 4096);
  transpose_cast<<<dim3(32, 128), tb, 0, stream>>>(pjw, wpjT, 4096, 1024);

  ln_row<<<16384, 256, 0, stream>>>(x, ln1w, ln1b, lnx);

  gemm128<1><<<1024, 256, 0, stream>>>(lnx, wqT, qb, nullptr, qfb, 16384, 1024, 1024, 8);
  gemm128<1><<<1024, 256, 0, stream>>>(lnx, wkT, kb, nullptr, kfb, 16384, 1024, 1024, 8);
  gemm128<0><<<1024, 256, 0, stream>>>(lnx, wvT, vb, nullptr, vbuf, 16384, 1024, 1024, 8);

  kv_part_kernel<<<512, 256, 0, stream>>>(kfb, vbuf, kvp, ksp);
  kv_reduce<<<64, 256, 0, stream>>>(kvp, ksp, kvf, ksf);
  attn_out_kernel<<<4096, 256, 0, stream>>>(qfb, kvf, ksf, attn);

  // y1 = x + attn @ o_w + o_b   (f32 into d_out)
  gemm128<2><<<1024, 256, 0, stream>>>(attn, woT, ob, x, out, 16384, 1024, 1024, 8);

  ln_row<<<16384, 256, 0, stream>>>(out, ln2w, ln2b, ln2h);

  gemm128<3><<<4096, 256, 0, stream>>>(ln2h, wfcT, fcb, nullptr, hmlp, 16384, 4096, 1024, 32);

  // out = y1 + h_mlp @ proj_w + proj_b  (in-place on d_out: read-before-write)
  gemm128<2><<<1024, 256, 0, stream>>>(hmlp, wpjT, pjb, out, out, 16384, 1024, 4096, 8);
}

// Round 5
// 715.162 us; speedup vs baseline: 1.0560x; 1.0560x over previous
//
#include <hip/hip_runtime.h>
#include <hip/hip_bf16.h>
#include <cstdint>
#include <cstddef>

typedef __bf16 bf16;
typedef __bf16 bf16x8 __attribute__((ext_vector_type(8)));
typedef __bf16 bf16x4 __attribute__((ext_vector_type(4)));
typedef float  f32x4  __attribute__((ext_vector_type(4)));

typedef __attribute__((address_space(1))) void gvoid_t;
typedef __attribute__((address_space(3))) void lvoid_t;

// async global->LDS, 16B per lane; LDS dest must be wave-uniform base (HW adds lane*16)
#define GLD_LDS16(g, l) __builtin_amdgcn_global_load_lds( \
    (gvoid_t*)(uintptr_t)(g), (lvoid_t*)(uint32_t)(uintptr_t)(l), 16, 0, 0)

#define SBAR() __builtin_amdgcn_s_barrier()
#define SCHED_FENCE() __builtin_amdgcn_sched_barrier(0)
#define WAIT_VM0() asm volatile("s_waitcnt vmcnt(0)" ::: "memory")
#define WAIT_VM8() asm volatile("s_waitcnt vmcnt(8)" ::: "memory")
#define WAIT_LGKM0() asm volatile("s_waitcnt lgkmcnt(0)" ::: "memory")

// ---------------------------------------------------------------------------
// Weight transpose + f32->bf16 cast:  in [R][C] f32  ->  out [C][R] bf16
// ---------------------------------------------------------------------------
__global__ __launch_bounds__(256) void transpose_cast(
    const float* __restrict__ in, bf16* __restrict__ out, int R, int C)
{
  __shared__ float tile[32][33];
  const int bx = blockIdx.x;   // C/32
  const int by = blockIdx.y;   // R/32
  const int tx = threadIdx.x;  // 0..31
  const int ty = threadIdx.y;  // 0..7
#pragma unroll
  for (int i = 0; i < 32; i += 8)
    tile[ty + i][tx] = in[(size_t)(by * 32 + ty + i) * C + bx * 32 + tx];
  __syncthreads();
#pragma unroll
  for (int i = 0; i < 32; i += 8)
    out[(size_t)(bx * 32 + ty + i) * R + by * 32 + tx] = (bf16)tile[tx][ty + i];
}

// pack q/k/v biases into one 3072-float vector
__global__ __launch_bounds__(256) void pack3(
    const float* __restrict__ a, const float* __restrict__ b,
    const float* __restrict__ c, float* __restrict__ o)
{
  const int i = blockIdx.x * 256 + threadIdx.x;
  o[i] = i < 1024 ? a[i] : (i < 2048 ? b[i - 1024] : c[i - 2048]);
}

// ---------------------------------------------------------------------------
// LayerNorm over H=1024, f32 in -> bf16 out. One block (256 thr) per row.
// ---------------------------------------------------------------------------
__global__ __launch_bounds__(256) void ln_row(
    const float* __restrict__ x, const float* __restrict__ w,
    const float* __restrict__ b, bf16* __restrict__ out)
{
  const int row = blockIdx.x;
  const int tid = threadIdx.x;
  const float4 v = ((const float4*)(x + (size_t)row * 1024))[tid];
  float s  = v.x + v.y + v.z + v.w;
  float ss = v.x * v.x + v.y * v.y + v.z * v.z + v.w * v.w;
#pragma unroll
  for (int off = 32; off > 0; off >>= 1) {
    s  += __shfl_down(s, off);
    ss += __shfl_down(ss, off);
  }
  __shared__ float red[8];
  const int wid = tid >> 6, lane = tid & 63;
  if (lane == 0) { red[wid] = s; red[4 + wid] = ss; }
  __syncthreads();
  s  = red[0] + red[1] + red[2] + red[3];
  ss = red[4] + red[5] + red[6] + red[7];
  const float mu   = s * (1.f / 1024.f);
  const float var  = ss * (1.f / 1024.f) - mu * mu;
  const float rstd = rsqrtf(var + 1e-5f);
  const float4 wv = ((const float4*)w)[tid];
  const float4 bv = ((const float4*)b)[tid];
  bf16x4 ov;
  ov[0] = (bf16)((v.x - mu) * rstd * wv.x + bv.x);
  ov[1] = (bf16)((v.y - mu) * rstd * wv.y + bv.y);
  ov[2] = (bf16)((v.z - mu) * rstd * wv.z + bv.z);
  ov[3] = (bf16)((v.w - mu) * rstd * wv.w + bv.w);
  *(bf16x4*)(out + (size_t)row * 1024 + tid * 4) = ov;
}

// ---------------------------------------------------------------------------
// 256x256 GEMM, BK=64, 8 waves (2Mx4N), 8x4 16x16x32 frags/wave.
// Depth-2 pipeline on 2 LDS buffers: fragments are register-captured before
// the MFMA cluster, so buffer d is dead mid-tile -> after lgkm0+barrier we
// stage tile kt+2 into d. Tile-end wait is vmcnt(8): waits only kt+1's loads
// (issued 2 tiles ago, already retired -> zero stall); kt+2's 8 loads remain
// in flight across the barrier (never drain to 0 in steady state).
// 8-slot XOR swizzle (slot ^= row&7, 16B slots) on BOTH gld_lds source and
// ds_read -> 0 bank conflicts.
// EPI: 0 bias->bf16 | 1 bias->elu+1->bf16 | 2 bias+resid->f32 |
//      3 bias->gelu->bf16 | 4 qkv merged (col<2048 elu+1, else plain)
// ---------------------------------------------------------------------------
template <int EPI>
__global__ __launch_bounds__(512, 2) void gemm256(
    const bf16* __restrict__ A, const bf16* __restrict__ BT,
    const float* __restrict__ bias, const float* __restrict__ resid,
    void* __restrict__ outp, int M, int N, int K, int nx)
{
  __shared__ __align__(16) char lds[131072];
  const int tid  = threadIdx.x;
  const int wid  = tid >> 6, lane = tid & 63;
  const int wr   = wid >> 2, wc = wid & 3;
  const int ln15 = lane & 15, lhi = lane >> 4;

  // chunked XCD swizzle + row-major logical tile order
  const int nwg = (int)gridDim.x;
  const int cpx = nwg >> 3;
  const int bid = (int)blockIdx.x;
  const int lg  = (bid & 7) * cpx + (bid >> 3);
  const int bx  = lg % nx, by = lg / nx;
  const int row0 = by << 8, col0 = bx << 8;

  // staging: 8 gld_lds per tile; issue i covers rows i*64+(tid>>3),
  // 16B slot (tid&7) in LDS holds global slot (tid&7)^(row&7).
  const int srow  = tid >> 3;                  // 0..63
  const int sslot = (tid & 7) ^ (srow & 7);
  const bf16* aS = A  + (size_t)(row0 + srow) * K + sslot * 8;
  const bf16* bS = BT + (size_t)(col0 + srow) * K + sslot * 8;
  const size_t rjump = (size_t)K << 6;         // +64 rows
  char* ldsW = lds + wid * 1024;               // per-wave linear dest base

  // swizzled read offsets (row&7 == ln15&7 for all frags: row steps are x16)
  const int rAb = (wr << 7) + ln15;
  const int rBb = (wc << 6) + ln15;
  const int sl0 = lhi ^ (ln15 & 7);
  const int sl1 = (4 + lhi) ^ (ln15 & 7);
  const int aOff0 = rAb * 128 + sl0 * 16;
  const int aOff1 = rAb * 128 + sl1 * 16;
  const int bOff0 = rBb * 128 + sl0 * 16 + 65536;
  const int bOff1 = rBb * 128 + sl1 * 16 + 65536;

  f32x4 acc[8][4] = {};
  const int nt = K >> 6;

#define STG(D, KT) do { \
    const bf16* ga_ = aS + (size_t)(KT) * 64; \
    const bf16* gb_ = bS + (size_t)(KT) * 64; \
    char* la_ = ldsW + (D) * 32768; \
    char* lb_ = la_ + 65536; \
    GLD_LDS16(ga_,             la_);         GLD_LDS16(gb_,             lb_); \
    GLD_LDS16(ga_ + rjump,     la_ + 8192);  GLD_LDS16(gb_ + rjump,     lb_ + 8192); \
    GLD_LDS16(ga_ + 2 * rjump, la_ + 16384); GLD_LDS16(gb_ + 2 * rjump, lb_ + 16384); \
    GLD_LDS16(ga_ + 3 * rjump, la_ + 24576); GLD_LDS16(gb_ + 3 * rjump, lb_ + 24576); \
  } while (0)

  // prologue: stage T0 and T1; wait T0 only (vmcnt(8))
  STG(0, 0);
  STG(1, 1);
  WAIT_VM8();
  SBAR();

  for (int kt = 0; kt < nt; ++kt) {
    const int d = kt & 1;
    const char* base = (const char*)lds + d * 32768;

    bf16x8 a0[8], b0[4], a1[8], b1[4];
#pragma unroll
    for (int m = 0; m < 8; ++m) a0[m] = *(const bf16x8*)(base + aOff0 + m * 2048);
#pragma unroll
    for (int n = 0; n < 4; ++n) b0[n] = *(const bf16x8*)(base + bOff0 + n * 2048);
#pragma unroll
    for (int m = 0; m < 8; ++m) a1[m] = *(const bf16x8*)(base + aOff1 + m * 2048);
#pragma unroll
    for (int n = 0; n < 4; ++n) b1[n] = *(const bf16x8*)(base + bOff1 + n * 2048);

    WAIT_LGKM0();      // own frag reads complete
    SBAR();            // all waves' reads complete -> buffer d is dead
    if (kt + 2 < nt) STG(d, kt + 2);   // overwrite dead buffer, DMA in flight
    SCHED_FENCE();

    __builtin_amdgcn_s_setprio(1);
#pragma unroll
    for (int m = 0; m < 8; ++m)
#pragma unroll
      for (int n = 0; n < 4; ++n)
        acc[m][n] = __builtin_amdgcn_mfma_f32_16x16x32_bf16(a0[m], b0[n], acc[m][n], 0, 0, 0);
#pragma unroll
    for (int m = 0; m < 8; ++m)
#pragma unroll
      for (int n = 0; n < 4; ++n)
        acc[m][n] = __builtin_amdgcn_mfma_f32_16x16x32_bf16(a1[m], b1[n], acc[m][n], 0, 0, 0);
    __builtin_amdgcn_s_setprio(0);

    if (kt + 2 < nt) { WAIT_VM8(); }       // kt+1's loads retired long ago
    else if (kt + 1 < nt) { WAIT_VM0(); }  // tail: drain kt+1 fully
    SBAR();
  }
#undef STG

  // epilogue
  const int lr4 = lhi << 2;
#pragma unroll
  for (int m = 0; m < 8; ++m) {
#pragma unroll
    for (int n = 0; n < 4; ++n) {
      const int c_i = col0 + wc * 64 + n * 16 + ln15;
      const float bv = bias[c_i];
#pragma unroll
      for (int j = 0; j < 4; ++j) {
        const int r_i = row0 + wr * 128 + m * 16 + lr4 + j;
        const size_t idx = (size_t)r_i * N + c_i;
        float val = acc[m][n][j] + bv;
        if constexpr (EPI == 0) {
          ((bf16*)outp)[idx] = (bf16)val;
        } else if constexpr (EPI == 1) {
          ((bf16*)outp)[idx] = (bf16)(val > 0.f ? val + 1.f : __expf(val));
        } else if constexpr (EPI == 2) {
          ((float*)outp)[idx] = val + resid[idx];
        } else if constexpr (EPI == 3) {
          const float u  = 0.7978845608028654f * (val + 0.044715f * val * val * val);
          const float th = 1.f - 2.f / (__expf(2.f * u) + 1.f);
          ((bf16*)outp)[idx] = (bf16)(0.5f * val * (1.f + th));
        } else {  // EPI 4: q,k cols get elu+1; v cols plain
          if (c_i < 2048)
            ((bf16*)outp)[idx] = (bf16)(val > 0.f ? val + 1.f : __expf(val));
          else
            ((bf16*)outp)[idx] = (bf16)val;
        }
      }
    }
  }
}

// ---------------------------------------------------------------------------
// kv partials: per (b,h) and 512-token chunk, kv[d][e] = sum_t kf[t,d]*v[t,e],
// ksum[d] = sum_t kf[t,d].  grid = 64 heads * 8 chunks.
// kf/v live in packed qkv buffer: row stride 3072, kf at col 1024+h*64,
// v at col 2048+h*64.
// ---------------------------------------------------------------------------
__global__ __launch_bounds__(256) void kv_part_kernel(
    const bf16* __restrict__ qkv, float* __restrict__ kv_part,
    float* __restrict__ ksum_part)
{
  const int bh = blockIdx.x >> 3, ch = blockIdx.x & 7;
  const int b = bh >> 4, h = bh & 15;
  const int tid = threadIdx.x;
  const int e = tid & 63, dg = tid >> 6;
  const size_t grow0 = (size_t)b * 4096 + (size_t)ch * 512;
  const size_t kbase = 1024 + (size_t)h * 64;
  __shared__ bf16 skf[8][64], sv[8][64];
  float accum[16];
#pragma unroll
  for (int i = 0; i < 16; ++i) accum[i] = 0.f;
  float ks = 0.f;
  const int tt = tid >> 5, cc = (tid & 31) << 1;
  for (int t0 = 0; t0 < 512; t0 += 8) {
    __syncthreads();
    const size_t base = (grow0 + t0 + tt) * 3072 + kbase + cc;
    *(uint32_t*)&skf[tt][cc] = *(const uint32_t*)(qkv + base);
    *(uint32_t*)&sv[tt][cc]  = *(const uint32_t*)(qkv + base + 1024);
    __syncthreads();
#pragma unroll
    for (int q = 0; q < 8; ++q) {
      const float vv = (float)sv[q][e];
#pragma unroll
      for (int dd = 0; dd < 16; ++dd)
        accum[dd] += (float)skf[q][dg * 16 + dd] * vv;
    }
    if (tid < 64) {
#pragma unroll
      for (int q = 0; q < 8; ++q) ks += (float)skf[q][tid];
    }
  }
  float* op = kv_part + (size_t)blockIdx.x * 4096 + (size_t)(dg * 16) * 64 + e;
#pragma unroll
  for (int dd = 0; dd < 16; ++dd) op[dd * 64] = accum[dd];
  if (tid < 64) ksum_part[(size_t)blockIdx.x * 64 + tid] = ks;
}

__global__ __launch_bounds__(256) void kv_reduce(
    const float* __restrict__ kvp, const float* __restrict__ ksp,
    float* __restrict__ kvf, float* __restrict__ ksf)
{
  const int bh = blockIdx.x;
  const int tid = threadIdx.x;
  for (int i = tid; i < 4096; i += 256) {
    float s = 0.f;
#pragma unroll
    for (int ch = 0; ch < 8; ++ch) s += kvp[((size_t)bh * 8 + ch) * 4096 + i];
    kvf[(size_t)bh * 4096 + i] = s;
  }
  if (tid < 64) {
    float s = 0.f;
#pragma unroll
    for (int ch = 0; ch < 8; ++ch) s += ksp[((size_t)bh * 8 + ch) * 64 + tid];
    ksf[(size_t)bh * 64 + tid] = s;
  }
}

// ---------------------------------------------------------------------------
// attn out: out[t,e] = (qf[t,:].kv[:,e]) / (qf[t,:].ksum + 1e-6) -> bf16
// qf lives in packed qkv buffer: row stride 3072, col h*64.
// ---------------------------------------------------------------------------
__global__ __launch_bounds__(256) void attn_out_kernel(
    const bf16* __restrict__ qkv, const float* __restrict__ kvf,
    const float* __restrict__ ksf, bf16* __restrict__ attn)
{
  const int bh = blockIdx.x >> 6, rb = blockIdx.x & 63;
  const int b = bh >> 4, h = bh & 15;
  const int tid = threadIdx.x;
  const int e = tid & 63, rbase = (tid >> 6) << 4;
  __shared__ __align__(16) bf16 sqf[64][64];
  __shared__ float sks[64];
  const size_t grow0 = (size_t)b * 4096 + (size_t)rb * 64;

  {
    const int rr = tid >> 2, c0 = (tid & 3) << 4;
    const bf16* src = qkv + (grow0 + rr) * 3072 + h * 64 + c0;
    *(bf16x8*)&sqf[rr][c0]     = *(const bf16x8*)src;
    *(bf16x8*)&sqf[rr][c0 + 8] = *(const bf16x8*)(src + 8);
  }
  if (tid < 64) sks[tid] = ksf[(size_t)bh * 64 + tid];

  float kcol[64];
#pragma unroll
  for (int d = 0; d < 64; ++d) kcol[d] = kvf[(size_t)bh * 4096 + d * 64 + e];

  __syncthreads();

  for (int rr = 0; rr < 16; ++rr) {
    const int r = rbase + rr;
    bf16x8 q8[8];
#pragma unroll
    for (int i = 0; i < 8; ++i) q8[i] = *(const bf16x8*)&sqf[r][i * 8];
    float sk = 0.f, sv = 0.f;
#pragma unroll
    for (int i = 0; i < 8; ++i)
#pragma unroll
      for (int jj = 0; jj < 8; ++jj) {
        const float qd = (float)q8[i][jj];
        sk += qd * sks[i * 8 + jj];
        sv += qd * kcol[i * 8 + jj];
      }
    attn[(grow0 + r) * 1024 + h * 64 + e] = (bf16)(sv / (sk + 1e-6f));
  }
}

// ---------------------------------------------------------------------------
// launch
// ---------------------------------------------------------------------------
extern "C" void kernel_launch(void* const* d_in, const int* in_sizes, int n_in,
                              void* d_out, int out_size, void* d_ws, size_t ws_size,
                              hipStream_t stream)
{
  const float* x    = (const float*)d_in[0];
  const float* ln1w = (const float*)d_in[1];
  const float* ln1b = (const float*)d_in[2];
  const float* qw   = (const float*)d_in[3];
  const float* qb   = (const float*)d_in[4];
  const float* kw   = (const float*)d_in[5];
  const float* kb   = (const float*)d_in[6];
  const float* vw   = (const float*)d_in[7];
  const float* vb   = (const float*)d_in[8];
  const float* ow   = (const float*)d_in[9];
  const float* ob   = (const float*)d_in[10];
  const float* ln2w = (const float*)d_in[11];
  const float* ln2b = (const float*)d_in[12];
  const float* fcw  = (const float*)d_in[13];
  const float* fcb  = (const float*)d_in[14];
  const float* pjw  = (const float*)d_in[15];
  const float* pjb  = (const float*)d_in[16];
  float* out = (float*)d_out;
  char* ws = (char*)d_ws;

  // region0 [0,134217728): lnx(32MB) + qkv(96MB) in phase 1; hmlp(128MB) in MLP phase.
  constexpr size_t O_LNX  = 0;
  constexpr size_t O_QKV  = 33554432;
  constexpr size_t O_HMLP = 0;
  constexpr size_t O_KVP  = 134217728;   // 8MB; also reused as qkv-bias scratch pre-attention
  constexpr size_t O_KSP  = 142606336;
  constexpr size_t O_KVF  = 142737408;
  constexpr size_t O_KSF  = 143785984;
  constexpr size_t O_ATTN = 143802368;
  constexpr size_t O_LN2  = 177356800;
  constexpr size_t O_WQ   = 210911232;   // wq/wk/wv transposed, contiguous = packed qkv weight
  constexpr size_t O_WO   = 217202688;
  constexpr size_t O_WFC  = 219299840;
  constexpr size_t O_WPJ  = 227688448;

  bf16* lnx   = (bf16*)(ws + O_LNX);
  bf16* qkv   = (bf16*)(ws + O_QKV);
  bf16* hmlp  = (bf16*)(ws + O_HMLP);
  float* kvp  = (float*)(ws + O_KVP);
  float* qkvb = (float*)(ws + O_KVP);    // 12KB, dead before kv_part runs
  float* ksp  = (float*)(ws + O_KSP);
  float* kvf  = (float*)(ws + O_KVF);
  float* ksf  = (float*)(ws + O_KSF);
  bf16* attn  = (bf16*)(ws + O_ATTN);
  bf16* ln2h  = (bf16*)(ws + O_LN2);
  bf16* wqkvT = (bf16*)(ws + O_WQ);
  bf16* woT   = (bf16*)(ws + O_WO);
  bf16* wfcT  = (bf16*)(ws + O_WFC);
  bf16* wpjT  = (bf16*)(ws + O_WPJ);

  const dim3 tb(32, 8);
  transpose_cast<<<dim3(32, 32),  tb, 0, stream>>>(qw,  wqkvT,                1024, 1024);
  transpose_cast<<<dim3(32, 32),  tb, 0, stream>>>(kw,  wqkvT + 1024 * 1024,  1024, 1024);
  transpose_cast<<<dim3(32, 32),  tb, 0, stream>>>(vw,  wqkvT + 2048 * 1024,  1024, 1024);
  transpose_cast<<<dim3(32, 32),  tb, 0, stream>>>(ow,  woT, 1024, 1024);
  transpose_cast<<<dim3(128, 32), tb, 0, stream>>>(fcw, wfcT, 1024, 4096);
  transpose_cast<<<dim3(32, 128), tb, 0, stream>>>(pjw, wpjT, 4096, 1024);
  pack3<<<12, 256, 0, stream>>>(qb, kb, vb, qkvb);

  ln_row<<<16384, 256, 0, stream>>>(x, ln1w, ln1b, lnx);

  // fused q|k|v projection: [16384,1024] x [1024,3072]
  gemm256<4><<<768, 512, 0, stream>>>(lnx, wqkvT, qkvb, nullptr, qkv, 16384, 3072, 1024, 12);

  kv_part_kernel<<<512, 256, 0, stream>>>(qkv, kvp, ksp);
  kv_reduce<<<64, 256, 0, stream>>>(kvp, ksp, kvf, ksf);
  attn_out_kernel<<<4096, 256, 0, stream>>>(qkv, kvf, ksf, attn);

  // y1 = x + attn @ o_w + o_b   (f32 into d_out)
  gemm256<2><<<256, 512, 0, stream>>>(attn, woT, ob, x, out, 16384, 1024, 1024, 4);

  ln_row<<<16384, 256, 0, stream>>>(out, ln2w, ln2b, ln2h);

  gemm256<3><<<1024, 512, 0, stream>>>(ln2h, wfcT, fcb, nullptr, hmlp, 16384, 4096, 1024, 16);

  // out = y1 + h_mlp @ proj_w + proj_b  (in-place on d_out: read-before-write)
  gemm256<2><<<256, 512, 0, stream>>>(hmlp, wpjT, pjb, out, out, 16384, 1024, 4096, 4);
}

// Round 6
// 701.864 us; speedup vs baseline: 1.0760x; 1.0189x over previous
//
#include <hip/hip_runtime.h>
#include <hip/hip_bf16.h>
#include <cstdint>
#include <cstddef>

typedef __bf16 bf16;
typedef __bf16 bf16x8 __attribute__((ext_vector_type(8)));
typedef __bf16 bf16x4 __attribute__((ext_vector_type(4)));
typedef float  f32x4  __attribute__((ext_vector_type(4)));

typedef __attribute__((address_space(1))) void gvoid_t;
typedef __attribute__((address_space(3))) void lvoid_t;

// async global->LDS, 16B per lane; LDS dest must be wave-uniform base (HW adds lane*16)
#define GLD_LDS16(g, l) __builtin_amdgcn_global_load_lds( \
    (gvoid_t*)(uintptr_t)(g), (lvoid_t*)(uint32_t)(uintptr_t)(l), 16, 0, 0)

#define SBAR() __builtin_amdgcn_s_barrier()
#define SCHED_FENCE() __builtin_amdgcn_sched_barrier(0)
#define WAIT_VMN(n) asm volatile("s_waitcnt vmcnt(" #n ")" ::: "memory")
#define WAIT_LGKM0() asm volatile("s_waitcnt lgkmcnt(0)" ::: "memory")

// ---------------------------------------------------------------------------
// Weight transpose + f32->bf16 cast:  in [R][C] f32  ->  out [C][R] bf16
// ---------------------------------------------------------------------------
__global__ __launch_bounds__(256) void transpose_cast(
    const float* __restrict__ in, bf16* __restrict__ out, int R, int C)
{
  __shared__ float tile[32][33];
  const int bx = blockIdx.x;   // C/32
  const int by = blockIdx.y;   // R/32
  const int tx = threadIdx.x;  // 0..31
  const int ty = threadIdx.y;  // 0..7
#pragma unroll
  for (int i = 0; i < 32; i += 8)
    tile[ty + i][tx] = in[(size_t)(by * 32 + ty + i) * C + bx * 32 + tx];
  __syncthreads();
#pragma unroll
  for (int i = 0; i < 32; i += 8)
    out[(size_t)(bx * 32 + ty + i) * R + by * 32 + tx] = (bf16)tile[tx][ty + i];
}

// pack q/k/v biases into one 3072-float vector
__global__ __launch_bounds__(256) void pack3(
    const float* __restrict__ a, const float* __restrict__ b,
    const float* __restrict__ c, float* __restrict__ o)
{
  const int i = blockIdx.x * 256 + threadIdx.x;
  o[i] = i < 1024 ? a[i] : (i < 2048 ? b[i - 1024] : c[i - 2048]);
}

// ---------------------------------------------------------------------------
// LayerNorm over H=1024, f32 in -> bf16 out. One block (256 thr) per row.
// ---------------------------------------------------------------------------
__global__ __launch_bounds__(256) void ln_row(
    const float* __restrict__ x, const float* __restrict__ w,
    const float* __restrict__ b, bf16* __restrict__ out)
{
  const int row = blockIdx.x;
  const int tid = threadIdx.x;
  const float4 v = ((const float4*)(x + (size_t)row * 1024))[tid];
  float s  = v.x + v.y + v.z + v.w;
  float ss = v.x * v.x + v.y * v.y + v.z * v.z + v.w * v.w;
#pragma unroll
  for (int off = 32; off > 0; off >>= 1) {
    s  += __shfl_down(s, off);
    ss += __shfl_down(ss, off);
  }
  __shared__ float red[8];
  const int wid = tid >> 6, lane = tid & 63;
  if (lane == 0) { red[wid] = s; red[4 + wid] = ss; }
  __syncthreads();
  s  = red[0] + red[1] + red[2] + red[3];
  ss = red[4] + red[5] + red[6] + red[7];
  const float mu   = s * (1.f / 1024.f);
  const float var  = ss * (1.f / 1024.f) - mu * mu;
  const float rstd = rsqrtf(var + 1e-5f);
  const float4 wv = ((const float4*)w)[tid];
  const float4 bv = ((const float4*)b)[tid];
  bf16x4 ov;
  ov[0] = (bf16)((v.x - mu) * rstd * wv.x + bv.x);
  ov[1] = (bf16)((v.y - mu) * rstd * wv.y + bv.y);
  ov[2] = (bf16)((v.z - mu) * rstd * wv.z + bv.z);
  ov[3] = (bf16)((v.w - mu) * rstd * wv.w + bv.w);
  *(bf16x4*)(out + (size_t)row * 1024 + tid * 4) = ov;
}

// ---------------------------------------------------------------------------
// 256x256 GEMM, BK=64, 8 waves (2Mx4N), faithful 4-phase/K-tile schedule.
// Phases: P1{read Ah0+Bh0(12), stage Ah0'}, P2{read Bh1(4), stage Bh0', vm(4)},
//         P3{read Ah1(8), stage Bh1'}, P4{stage Ah1', MFMA, vm(2)}.
// Each phase: barrier; lgkm0; sched_fence; 16 MFMA (setprio-wrapped); barrier.
// Stage units are first-use aligned: A-h0 = row chunks {0-63,128-191} (what
// all waves' mh0 frags touch), B halves = 32-row stripes (nh) gathered via
// per-lane global addresses into reordered LDS rows rB' = nh*128+wc*32+r.
// Counted vmcnt never drains to 0 in steady state (2 loads stay in flight).
// 8-slot XOR swizzle (slot ^= row&7) on BOTH gld source and ds_read -> 0 bc.
// EPI: 0 bias->bf16 | 1 bias->elu+1->bf16 | 2 bias+resid->f32 |
//      3 bias->gelu->bf16 | 4 qkv merged (col<2048 elu+1, else plain)
// ---------------------------------------------------------------------------
template <int EPI>
__global__ __launch_bounds__(512, 2) void gemm256(
    const bf16* __restrict__ A, const bf16* __restrict__ BT,
    const float* __restrict__ bias, const float* __restrict__ resid,
    void* __restrict__ outp, int M, int N, int K, int nx)
{
  __shared__ __align__(16) char lds[131072];
  const int tid  = threadIdx.x;
  const int wid  = tid >> 6, lane = tid & 63;
  const int wr   = wid >> 2, wc = wid & 3;
  const int ln15 = lane & 15, lhi = lane >> 4;

  // chunked XCD swizzle + row-major logical tile order
  const int nwg = (int)gridDim.x;
  const int cpx = nwg >> 3;
  const int bid = (int)blockIdx.x;
  const int lg  = (bid & 7) * cpx + (bid >> 3);
  const int bx  = lg % nx, by = lg / nx;
  const int row0 = by << 8, col0 = bx << 8;

  // ---- staging pointers ----
  // A: thread covers row srowA of a 64-row chunk; slot XOR by row.
  const int srowA = tid >> 3;
  const int sslA  = (tid & 7) ^ (srowA & 7);
  const bf16* aS  = A + (size_t)(row0 + srowA) * K + sslA * 8;
  const size_t rjK = (size_t)K << 6;   // +64 rows
  // B: stripe gather. u=tid>>3; global row = (u>>5)*64 + (u&31) (+ j*128 + nh*32)
  const int u8    = tid >> 3, s8 = tid & 7;
  const int gRowB = ((u8 >> 5) << 6) + (u8 & 31);
  const int sslB  = s8 ^ (u8 & 7);
  const bf16* bS  = BT + (size_t)(col0 + gRowB) * K + sslB * 8;

  char* ldsAw = lds + wid * 1024;              // + d*32768 + chunk*8192
  char* ldsBw = lds + 65536 + wid * 1024;      // + d*32768 + nh*16384 + j*8192

  // ---- read offsets (swizzled) ----
  const int slk0 = (lhi ^ (ln15 & 7)) << 4;
  const int slk1 = ((4 + lhi) ^ (ln15 & 7)) << 4;
  const int rowA0 = ((wr << 7) + ln15) * 128;          // + mh*8192 + m*2048
  const int rowB0 = 65536 + (wc * 32 + ln15) * 128;    // + nh*16384 + n*2048

  f32x4 acc[8][4] = {};
  bf16x8 a[4][2], b0[2][2], b1[2][2];
  const int nt = K >> 6;

#define STG_A(D, KT, I) GLD_LDS16(aS + (size_t)(I) * rjK + (size_t)(KT) * 64, \
                                  ldsAw + (D) * 32768 + (I) * 8192)
#define STG_B(D, KT, NH, J) GLD_LDS16(bS + (size_t)((J) * 128 + (NH) * 32) * K + (size_t)(KT) * 64, \
                                      ldsBw + (D) * 32768 + (NH) * 16384 + (J) * 8192)
#define RD_A(D, MH) do { _Pragma("unroll") \
    for (int m_ = 0; m_ < 4; ++m_) { \
      a[m_][0] = *(const bf16x8*)(lds + (D) * 32768 + rowA0 + (MH) * 8192 + m_ * 2048 + slk0); \
      a[m_][1] = *(const bf16x8*)(lds + (D) * 32768 + rowA0 + (MH) * 8192 + m_ * 2048 + slk1); \
    } } while (0)
#define RD_B(D, NH, DST) do { _Pragma("unroll") \
    for (int n_ = 0; n_ < 2; ++n_) { \
      DST[n_][0] = *(const bf16x8*)(lds + (D) * 32768 + rowB0 + (NH) * 16384 + n_ * 2048 + slk0); \
      DST[n_][1] = *(const bf16x8*)(lds + (D) * 32768 + rowB0 + (NH) * 16384 + n_ * 2048 + slk1); \
    } } while (0)
#define MFMA8(MH, NH, BSRC) do { \
    __builtin_amdgcn_s_setprio(1); \
    _Pragma("unroll") for (int m_ = 0; m_ < 4; ++m_) \
    _Pragma("unroll") for (int n_ = 0; n_ < 2; ++n_) { \
      acc[(MH) * 4 + m_][(NH) * 2 + n_] = __builtin_amdgcn_mfma_f32_16x16x32_bf16( \
          a[m_][0], BSRC[n_][0], acc[(MH) * 4 + m_][(NH) * 2 + n_], 0, 0, 0); \
      acc[(MH) * 4 + m_][(NH) * 2 + n_] = __builtin_amdgcn_mfma_f32_16x16x32_bf16( \
          a[m_][1], BSRC[n_][1], acc[(MH) * 4 + m_][(NH) * 2 + n_], 0, 0, 0); \
    } \
    __builtin_amdgcn_s_setprio(0); } while (0)

  // prologue: stage all of T0, full drain once
  STG_A(0, 0, 0); STG_A(0, 0, 2);
  STG_B(0, 0, 0, 0); STG_B(0, 0, 0, 1);
  STG_B(0, 0, 1, 0); STG_B(0, 0, 1, 1);
  STG_A(0, 0, 1); STG_A(0, 0, 3);
  WAIT_VMN(0);
  SBAR(); SCHED_FENCE();

  for (int kt = 0; kt < nt - 1; ++kt) {
    const int d = kt & 1, dn = d ^ 1;
    // ---- P1: read Ah0 + Bh0; stage Ah0' ----
    RD_A(d, 0); RD_B(d, 0, b0);
    STG_A(dn, kt + 1, 0); STG_A(dn, kt + 1, 2);
    SBAR(); WAIT_LGKM0(); SCHED_FENCE();
    MFMA8(0, 0, b0);
    SBAR(); SCHED_FENCE();
    // ---- P2: read Bh1; stage Bh0'; vm(4) retires prev Ah1 ----
    RD_B(d, 1, b1);
    STG_B(dn, kt + 1, 0, 0); STG_B(dn, kt + 1, 0, 1);
    WAIT_VMN(4);
    SBAR(); WAIT_LGKM0(); SCHED_FENCE();
    MFMA8(0, 1, b1);
    SBAR(); SCHED_FENCE();
    // ---- P3: read Ah1; stage Bh1' ----
    RD_A(d, 1);
    STG_B(dn, kt + 1, 1, 0); STG_B(dn, kt + 1, 1, 1);
    SBAR(); WAIT_LGKM0(); SCHED_FENCE();
    MFMA8(1, 0, b0);
    SBAR(); SCHED_FENCE();
    // ---- P4: stage Ah1'; vm(2) -> Ah0'/Bh0'/Bh1' retired for next tile ----
    STG_A(dn, kt + 1, 1); STG_A(dn, kt + 1, 3);
    MFMA8(1, 1, b1);
    WAIT_VMN(2);
    SBAR(); SCHED_FENCE();
  }

  // peeled last tile (no staging; tail drains)
  {
    const int d = (nt - 1) & 1;
    RD_A(d, 0); RD_B(d, 0, b0);
    SBAR(); WAIT_LGKM0(); SCHED_FENCE();
    MFMA8(0, 0, b0);
    SBAR(); SCHED_FENCE();
    RD_B(d, 1, b1);
    WAIT_VMN(0);
    SBAR(); WAIT_LGKM0(); SCHED_FENCE();
    MFMA8(0, 1, b1);
    SBAR(); SCHED_FENCE();
    RD_A(d, 1);
    WAIT_LGKM0(); SCHED_FENCE();
    MFMA8(1, 0, b0);
    MFMA8(1, 1, b1);
  }
#undef STG_A
#undef STG_B
#undef RD_A
#undef RD_B
#undef MFMA8

  // epilogue
  const int lr4 = lhi << 2;
#pragma unroll
  for (int m = 0; m < 8; ++m) {
#pragma unroll
    for (int n = 0; n < 4; ++n) {
      const int c_i = col0 + wc * 64 + n * 16 + ln15;
      const float bv = bias[c_i];
#pragma unroll
      for (int j = 0; j < 4; ++j) {
        const int r_i = row0 + wr * 128 + m * 16 + lr4 + j;
        const size_t idx = (size_t)r_i * N + c_i;
        float val = acc[m][n][j] + bv;
        if constexpr (EPI == 0) {
          ((bf16*)outp)[idx] = (bf16)val;
        } else if constexpr (EPI == 1) {
          ((bf16*)outp)[idx] = (bf16)(val > 0.f ? val + 1.f : __expf(val));
        } else if constexpr (EPI == 2) {
          ((float*)outp)[idx] = val + resid[idx];
        } else if constexpr (EPI == 3) {
          const float u  = 0.7978845608028654f * (val + 0.044715f * val * val * val);
          const float th = 1.f - 2.f / (__expf(2.f * u) + 1.f);
          ((bf16*)outp)[idx] = (bf16)(0.5f * val * (1.f + th));
        } else {  // EPI 4: q,k cols get elu+1; v cols plain
          if (c_i < 2048)
            ((bf16*)outp)[idx] = (bf16)(val > 0.f ? val + 1.f : __expf(val));
          else
            ((bf16*)outp)[idx] = (bf16)val;
        }
      }
    }
  }
}

// ---------------------------------------------------------------------------
// kv partials: per (b,h) and 512-token chunk, kv[d][e] = sum_t kf[t,d]*v[t,e],
// ksum[d] = sum_t kf[t,d].  grid = 64 heads * 8 chunks.
// kf/v live in packed qkv buffer: row stride 3072.
// ---------------------------------------------------------------------------
__global__ __launch_bounds__(256) void kv_part_kernel(
    const bf16* __restrict__ qkv, float* __restrict__ kv_part,
    float* __restrict__ ksum_part)
{
  const int bh = blockIdx.x >> 3, ch = blockIdx.x & 7;
  const int b = bh >> 4, h = bh & 15;
  const int tid = threadIdx.x;
  const int e = tid & 63, dg = tid >> 6;
  const size_t grow0 = (size_t)b * 4096 + (size_t)ch * 512;
  const size_t kbase = 1024 + (size_t)h * 64;
  __shared__ bf16 skf[8][64], sv[8][64];
  float accum[16];
#pragma unroll
  for (int i = 0; i < 16; ++i) accum[i] = 0.f;
  float ks = 0.f;
  const int tt = tid >> 5, cc = (tid & 31) << 1;
  for (int t0 = 0; t0 < 512; t0 += 8) {
    __syncthreads();
    const size_t base = (grow0 + t0 + tt) * 3072 + kbase + cc;
    *(uint32_t*)&skf[tt][cc] = *(const uint32_t*)(qkv + base);
    *(uint32_t*)&sv[tt][cc]  = *(const uint32_t*)(qkv + base + 1024);
    __syncthreads();
#pragma unroll
    for (int q = 0; q < 8; ++q) {
      const float vv = (float)sv[q][e];
#pragma unroll
      for (int dd = 0; dd < 16; ++dd)
        accum[dd] += (float)skf[q][dg * 16 + dd] * vv;
    }
    if (tid < 64) {
#pragma unroll
      for (int q = 0; q < 8; ++q) ks += (float)skf[q][tid];
    }
  }
  float* op = kv_part + (size_t)blockIdx.x * 4096 + (size_t)(dg * 16) * 64 + e;
#pragma unroll
  for (int dd = 0; dd < 16; ++dd) op[dd * 64] = accum[dd];
  if (tid < 64) ksum_part[(size_t)blockIdx.x * 64 + tid] = ks;
}

__global__ __launch_bounds__(256) void kv_reduce(
    const float* __restrict__ kvp, const float* __restrict__ ksp,
    float* __restrict__ kvf, float* __restrict__ ksf)
{
  const int bh = blockIdx.x;
  const int tid = threadIdx.x;
  for (int i = tid; i < 4096; i += 256) {
    float s = 0.f;
#pragma unroll
    for (int ch = 0; ch < 8; ++ch) s += kvp[((size_t)bh * 8 + ch) * 4096 + i];
    kvf[(size_t)bh * 4096 + i] = s;
  }
  if (tid < 64) {
    float s = 0.f;
#pragma unroll
    for (int ch = 0; ch < 8; ++ch) s += ksp[((size_t)bh * 8 + ch) * 64 + tid];
    ksf[(size_t)bh * 64 + tid] = s;
  }
}

// ---------------------------------------------------------------------------
// attn out: out[t,e] = (qf[t,:].kv[:,e]) / (qf[t,:].ksum + 1e-6) -> bf16
// qf lives in packed qkv buffer: row stride 3072, col h*64.
// ---------------------------------------------------------------------------
__global__ __launch_bounds__(256) void attn_out_kernel(
    const bf16* __restrict__ qkv, const float* __restrict__ kvf,
    const float* __restrict__ ksf, bf16* __restrict__ attn)
{
  const int bh = blockIdx.x >> 6, rb = blockIdx.x & 63;
  const int b = bh >> 4, h = bh & 15;
  const int tid = threadIdx.x;
  const int e = tid & 63, rbase = (tid >> 6) << 4;
  __shared__ __align__(16) bf16 sqf[64][64];
  __shared__ float sks[64];
  const size_t grow0 = (size_t)b * 4096 + (size_t)rb * 64;

  {
    const int rr = tid >> 2, c0 = (tid & 3) << 4;
    const bf16* src = qkv + (grow0 + rr) * 3072 + h * 64 + c0;
    *(bf16x8*)&sqf[rr][c0]     = *(const bf16x8*)src;
    *(bf16x8*)&sqf[rr][c0 + 8] = *(const bf16x8*)(src + 8);
  }
  if (tid < 64) sks[tid] = ksf[(size_t)bh * 64 + tid];

  float kcol[64];
#pragma unroll
  for (int d = 0; d < 64; ++d) kcol[d] = kvf[(size_t)bh * 4096 + d * 64 + e];

  __syncthreads();

  for (int rr = 0; rr < 16; ++rr) {
    const int r = rbase + rr;
    bf16x8 q8[8];
#pragma unroll
    for (int i = 0; i < 8; ++i) q8[i] = *(const bf16x8*)&sqf[r][i * 8];
    float sk = 0.f, sv = 0.f;
#pragma unroll
    for (int i = 0; i < 8; ++i)
#pragma unroll
      for (int jj = 0; jj < 8; ++jj) {
        const float qd = (float)q8[i][jj];
        sk += qd * sks[i * 8 + jj];
        sv += qd * kcol[i * 8 + jj];
      }
    attn[(grow0 + r) * 1024 + h * 64 + e] = (bf16)(sv / (sk + 1e-6f));
  }
}

// ---------------------------------------------------------------------------
// launch
// ---------------------------------------------------------------------------
extern "C" void kernel_launch(void* const* d_in, const int* in_sizes, int n_in,
                              void* d_out, int out_size, void* d_ws, size_t ws_size,
                              hipStream_t stream)
{
  const float* x    = (const float*)d_in[0];
  const float* ln1w = (const float*)d_in[1];
  const float* ln1b = (const float*)d_in[2];
  const float* qw   = (const float*)d_in[3];
  const float* qb   = (const float*)d_in[4];
  const float* kw   = (const float*)d_in[5];
  const float* kb   = (const float*)d_in[6];
  const float* vw   = (const float*)d_in[7];
  const float* vb   = (const float*)d_in[8];
  const float* ow   = (const float*)d_in[9];
  const float* ob   = (const float*)d_in[10];
  const float* ln2w = (const float*)d_in[11];
  const float* ln2b = (const float*)d_in[12];
  const float* fcw  = (const float*)d_in[13];
  const float* fcb  = (const float*)d_in[14];
  const float* pjw  = (const float*)d_in[15];
  const float* pjb  = (const float*)d_in[16];
  float* out = (float*)d_out;
  char* ws = (char*)d_ws;

  constexpr size_t O_LNX  = 0;
  constexpr size_t O_QKV  = 33554432;
  constexpr size_t O_HMLP = 0;
  constexpr size_t O_KVP  = 134217728;
  constexpr size_t O_KSP  = 142606336;
  constexpr size_t O_KVF  = 142737408;
  constexpr size_t O_KSF  = 143785984;
  constexpr size_t O_ATTN = 143802368;
  constexpr size_t O_LN2  = 177356800;
  constexpr size_t O_WQ   = 210911232;
  constexpr size_t O_WO   = 217202688;
  constexpr size_t O_WFC  = 219299840;
  constexpr size_t O_WPJ  = 227688448;

  bf16* lnx   = (bf16*)(ws + O_LNX);
  bf16* qkv   = (bf16*)(ws + O_QKV);
  bf16* hmlp  = (bf16*)(ws + O_HMLP);
  float* kvp  = (float*)(ws + O_KVP);
  float* qkvb = (float*)(ws + O_KVP);    // 12KB, dead before kv_part runs
  float* ksp  = (float*)(ws + O_KSP);
  float* kvf  = (float*)(ws + O_KVF);
  float* ksf  = (float*)(ws + O_KSF);
  bf16* attn  = (bf16*)(ws + O_ATTN);
  bf16* ln2h  = (bf16*)(ws + O_LN2);
  bf16* wqkvT = (bf16*)(ws + O_WQ);
  bf16* woT   = (bf16*)(ws + O_WO);
  bf16* wfcT  = (bf16*)(ws + O_WFC);
  bf16* wpjT  = (bf16*)(ws + O_WPJ);

  const dim3 tb(32, 8);
  transpose_cast<<<dim3(32, 32),  tb, 0, stream>>>(qw,  wqkvT,               1024, 1024);
  transpose_cast<<<dim3(32, 32),  tb, 0, stream>>>(kw,  wqkvT + 1024 * 1024, 1024, 1024);
  transpose_cast<<<dim3(32, 32),  tb, 0, stream>>>(vw,  wqkvT + 2048 * 1024, 1024, 1024);
  transpose_cast<<<dim3(32, 32),  tb, 0, stream>>>(ow,  woT, 1024, 1024);
  transpose_cast<<<dim3(128, 32), tb, 0, stream>>>(fcw, wfcT, 1024, 4096);
  transpose_cast<<<dim3(32, 128), tb, 0, stream>>>(pjw, wpjT, 4096, 1024);
  pack3<<<12, 256, 0, stream>>>(qb, kb, vb, qkvb);

  ln_row<<<16384, 256, 0, stream>>>(x, ln1w, ln1b, lnx);

  // fused q|k|v projection: [16384,1024] x [1024,3072]
  gemm256<4><<<768, 512, 0, stream>>>(lnx, wqkvT, qkvb, nullptr, qkv, 16384, 3072, 1024, 12);

  kv_part_kernel<<<512, 256, 0, stream>>>(qkv, kvp, ksp);
  kv_reduce<<<64, 256, 0, stream>>>(kvp, ksp, kvf, ksf);
  attn_out_kernel<<<4096, 256, 0, stream>>>(qkv, kvf, ksf, attn);

  // y1 = x + attn @ o_w + o_b   (f32 into d_out)
  gemm256<2><<<256, 512, 0, stream>>>(attn, woT, ob, x, out, 16384, 1024, 1024, 4);

  ln_row<<<16384, 256, 0, stream>>>(out, ln2w, ln2b, ln2h);

  gemm256<3><<<1024, 512, 0, stream>>>(ln2h, wfcT, fcb, nullptr, hmlp, 16384, 4096, 1024, 16);

  // out = y1 + h_mlp @ proj_w + proj_b  (in-place on d_out: read-before-write)
  gemm256<2><<<256, 512, 0, stream>>>(hmlp, wpjT, pjb, out, out, 16384, 1024, 4096, 4);
}

// Round 7
// 606.886 us; speedup vs baseline: 1.2444x; 1.1565x over previous
//
#include <hip/hip_runtime.h>
#include <hip/hip_bf16.h>
#include <cstdint>
#include <cstddef>

typedef __bf16 bf16;
typedef __bf16 bf16x8 __attribute__((ext_vector_type(8)));
typedef __bf16 bf16x4 __attribute__((ext_vector_type(4)));
typedef float  f32x4  __attribute__((ext_vector_type(4)));

typedef __attribute__((address_space(1))) void gvoid_t;
typedef __attribute__((address_space(3))) void lvoid_t;

// async global->LDS, 16B per lane; LDS dest must be wave-uniform base (HW adds lane*16)
#define GLD_LDS16(g, l) __builtin_amdgcn_global_load_lds( \
    (gvoid_t*)(uintptr_t)(g), (lvoid_t*)(uint32_t)(uintptr_t)(l), 16, 0, 0)

#define SBAR() __builtin_amdgcn_s_barrier()
#define SCHED_FENCE() __builtin_amdgcn_sched_barrier(0)
#define WAIT_VMN(n) asm volatile("s_waitcnt vmcnt(" #n ")" ::: "memory")
#define WAIT_LGKM0() asm volatile("s_waitcnt lgkmcnt(0)" ::: "memory")

// ---------------------------------------------------------------------------
// 4x fused weight transpose + f32->bf16 cast (1024x1024 each): q,k,v -> wqkvT
// (contiguous), o -> woT.
// ---------------------------------------------------------------------------
__global__ __launch_bounds__(256) void transpose4(
    const float* __restrict__ qw, const float* __restrict__ kw,
    const float* __restrict__ vw, const float* __restrict__ ow,
    bf16* __restrict__ wqkvT, bf16* __restrict__ woT)
{
  __shared__ float tile[32][33];
  const int z = blockIdx.z;
  const float* in = z == 0 ? qw : (z == 1 ? kw : (z == 2 ? vw : ow));
  bf16* out = z == 3 ? woT : (wqkvT + (size_t)z * 1024 * 1024);
  const int bx = blockIdx.x, by = blockIdx.y;
  const int tx = threadIdx.x, ty = threadIdx.y;
#pragma unroll
  for (int i = 0; i < 32; i += 8)
    tile[ty + i][tx] = in[(size_t)(by * 32 + ty + i) * 1024 + bx * 32 + tx];
  __syncthreads();
#pragma unroll
  for (int i = 0; i < 32; i += 8)
    out[(size_t)(bx * 32 + ty + i) * 1024 + by * 32 + tx] = (bf16)tile[tx][ty + i];
}

// general transpose for fc/proj weights
__global__ __launch_bounds__(256) void transpose_cast(
    const float* __restrict__ in, bf16* __restrict__ out, int R, int C)
{
  __shared__ float tile[32][33];
  const int bx = blockIdx.x, by = blockIdx.y;
  const int tx = threadIdx.x, ty = threadIdx.y;
#pragma unroll
  for (int i = 0; i < 32; i += 8)
    tile[ty + i][tx] = in[(size_t)(by * 32 + ty + i) * C + bx * 32 + tx];
  __syncthreads();
#pragma unroll
  for (int i = 0; i < 32; i += 8)
    out[(size_t)(bx * 32 + ty + i) * R + by * 32 + tx] = (bf16)tile[tx][ty + i];
}

// pack q/k/v biases into one 3072-float vector
__global__ __launch_bounds__(256) void pack3(
    const float* __restrict__ a, const float* __restrict__ b,
    const float* __restrict__ c, float* __restrict__ o)
{
  const int i = blockIdx.x * 256 + threadIdx.x;
  o[i] = i < 1024 ? a[i] : (i < 2048 ? b[i - 1024] : c[i - 2048]);
}

// ---------------------------------------------------------------------------
// LayerNorm over H=1024, f32 in -> bf16 out. One block (256 thr) per row.
// ---------------------------------------------------------------------------
__global__ __launch_bounds__(256) void ln_row(
    const float* __restrict__ x, const float* __restrict__ w,
    const float* __restrict__ b, bf16* __restrict__ out)
{
  const int row = blockIdx.x;
  const int tid = threadIdx.x;
  const float4 v = ((const float4*)(x + (size_t)row * 1024))[tid];
  float s  = v.x + v.y + v.z + v.w;
  float ss = v.x * v.x + v.y * v.y + v.z * v.z + v.w * v.w;
#pragma unroll
  for (int off = 32; off > 0; off >>= 1) {
    s  += __shfl_down(s, off);
    ss += __shfl_down(ss, off);
  }
  __shared__ float red[8];
  const int wid = tid >> 6, lane = tid & 63;
  if (lane == 0) { red[wid] = s; red[4 + wid] = ss; }
  __syncthreads();
  s  = red[0] + red[1] + red[2] + red[3];
  ss = red[4] + red[5] + red[6] + red[7];
  const float mu   = s * (1.f / 1024.f);
  const float var  = ss * (1.f / 1024.f) - mu * mu;
  const float rstd = rsqrtf(var + 1e-5f);
  const float4 wv = ((const float4*)w)[tid];
  const float4 bv = ((const float4*)b)[tid];
  bf16x4 ov;
  ov[0] = (bf16)((v.x - mu) * rstd * wv.x + bv.x);
  ov[1] = (bf16)((v.y - mu) * rstd * wv.y + bv.y);
  ov[2] = (bf16)((v.z - mu) * rstd * wv.z + bv.z);
  ov[3] = (bf16)((v.w - mu) * rstd * wv.w + bv.w);
  *(bf16x4*)(out + (size_t)row * 1024 + tid * 4) = ov;
}

// ---------------------------------------------------------------------------
// 256x256 GEMM, BK=64, 8 waves (2Mx4N), 4-phase/K-tile schedule (r6 best).
// EPI: 0 bias->bf16 | 1 bias->elu+1->bf16 | 2 bias+resid->f32 |
//      3 bias->gelu->bf16 | 4 qkv merged (col<2048 elu+1, else plain)
// ---------------------------------------------------------------------------
template <int EPI>
__global__ __launch_bounds__(512, 2) void gemm256(
    const bf16* __restrict__ A, const bf16* __restrict__ BT,
    const float* __restrict__ bias, const float* __restrict__ resid,
    void* __restrict__ outp, int M, int N, int K, int nx)
{
  __shared__ __align__(16) char lds[131072];
  const int tid  = threadIdx.x;
  const int wid  = tid >> 6, lane = tid & 63;
  const int wr   = wid >> 2, wc = wid & 3;
  const int ln15 = lane & 15, lhi = lane >> 4;

  const int nwg = (int)gridDim.x;
  const int cpx = nwg >> 3;
  const int bid = (int)blockIdx.x;
  const int lg  = (bid & 7) * cpx + (bid >> 3);
  const int bx  = lg % nx, by = lg / nx;
  const int row0 = by << 8, col0 = bx << 8;

  const int srowA = tid >> 3;
  const int sslA  = (tid & 7) ^ (srowA & 7);
  const bf16* aS  = A + (size_t)(row0 + srowA) * K + sslA * 8;
  const size_t rjK = (size_t)K << 6;
  const int u8    = tid >> 3, s8 = tid & 7;
  const int gRowB = ((u8 >> 5) << 6) + (u8 & 31);
  const int sslB  = s8 ^ (u8 & 7);
  const bf16* bS  = BT + (size_t)(col0 + gRowB) * K + sslB * 8;

  char* ldsAw = lds + wid * 1024;
  char* ldsBw = lds + 65536 + wid * 1024;

  const int slk0 = (lhi ^ (ln15 & 7)) << 4;
  const int slk1 = ((4 + lhi) ^ (ln15 & 7)) << 4;
  const int rowA0 = ((wr << 7) + ln15) * 128;
  const int rowB0 = 65536 + (wc * 32 + ln15) * 128;

  f32x4 acc[8][4] = {};
  bf16x8 a[4][2], b0[2][2], b1[2][2];
  const int nt = K >> 6;

#define STG_A(D, KT, I) GLD_LDS16(aS + (size_t)(I) * rjK + (size_t)(KT) * 64, \
                                  ldsAw + (D) * 32768 + (I) * 8192)
#define STG_B(D, KT, NH, J) GLD_LDS16(bS + (size_t)((J) * 128 + (NH) * 32) * K + (size_t)(KT) * 64, \
                                      ldsBw + (D) * 32768 + (NH) * 16384 + (J) * 8192)
#define RD_A(D, MH) do { _Pragma("unroll") \
    for (int m_ = 0; m_ < 4; ++m_) { \
      a[m_][0] = *(const bf16x8*)(lds + (D) * 32768 + rowA0 + (MH) * 8192 + m_ * 2048 + slk0); \
      a[m_][1] = *(const bf16x8*)(lds + (D) * 32768 + rowA0 + (MH) * 8192 + m_ * 2048 + slk1); \
    } } while (0)
#define RD_B(D, NH, DST) do { _Pragma("unroll") \
    for (int n_ = 0; n_ < 2; ++n_) { \
      DST[n_][0] = *(const bf16x8*)(lds + (D) * 32768 + rowB0 + (NH) * 16384 + n_ * 2048 + slk0); \
      DST[n_][1] = *(const bf16x8*)(lds + (D) * 32768 + rowB0 + (NH) * 16384 + n_ * 2048 + slk1); \
    } } while (0)
#define MFMA8(MH, NH, BSRC) do { \
    __builtin_amdgcn_s_setprio(1); \
    _Pragma("unroll") for (int m_ = 0; m_ < 4; ++m_) \
    _Pragma("unroll") for (int n_ = 0; n_ < 2; ++n_) { \
      acc[(MH) * 4 + m_][(NH) * 2 + n_] = __builtin_amdgcn_mfma_f32_16x16x32_bf16( \
          a[m_][0], BSRC[n_][0], acc[(MH) * 4 + m_][(NH) * 2 + n_], 0, 0, 0); \
      acc[(MH) * 4 + m_][(NH) * 2 + n_] = __builtin_amdgcn_mfma_f32_16x16x32_bf16( \
          a[m_][1], BSRC[n_][1], acc[(MH) * 4 + m_][(NH) * 2 + n_], 0, 0, 0); \
    } \
    __builtin_amdgcn_s_setprio(0); } while (0)

  STG_A(0, 0, 0); STG_A(0, 0, 2);
  STG_B(0, 0, 0, 0); STG_B(0, 0, 0, 1);
  STG_B(0, 0, 1, 0); STG_B(0, 0, 1, 1);
  STG_A(0, 0, 1); STG_A(0, 0, 3);
  WAIT_VMN(0);
  SBAR(); SCHED_FENCE();

  for (int kt = 0; kt < nt - 1; ++kt) {
    const int d = kt & 1, dn = d ^ 1;
    RD_A(d, 0); RD_B(d, 0, b0);
    STG_A(dn, kt + 1, 0); STG_A(dn, kt + 1, 2);
    SBAR(); WAIT_LGKM0(); SCHED_FENCE();
    MFMA8(0, 0, b0);
    SBAR(); SCHED_FENCE();
    RD_B(d, 1, b1);
    STG_B(dn, kt + 1, 0, 0); STG_B(dn, kt + 1, 0, 1);
    WAIT_VMN(4);
    SBAR(); WAIT_LGKM0(); SCHED_FENCE();
    MFMA8(0, 1, b1);
    SBAR(); SCHED_FENCE();
    RD_A(d, 1);
    STG_B(dn, kt + 1, 1, 0); STG_B(dn, kt + 1, 1, 1);
    SBAR(); WAIT_LGKM0(); SCHED_FENCE();
    MFMA8(1, 0, b0);
    SBAR(); SCHED_FENCE();
    STG_A(dn, kt + 1, 1); STG_A(dn, kt + 1, 3);
    MFMA8(1, 1, b1);
    WAIT_VMN(2);
    SBAR(); SCHED_FENCE();
  }

  {
    const int d = (nt - 1) & 1;
    RD_A(d, 0); RD_B(d, 0, b0);
    SBAR(); WAIT_LGKM0(); SCHED_FENCE();
    MFMA8(0, 0, b0);
    SBAR(); SCHED_FENCE();
    RD_B(d, 1, b1);
    WAIT_VMN(0);
    SBAR(); WAIT_LGKM0(); SCHED_FENCE();
    MFMA8(0, 1, b1);
    SBAR(); SCHED_FENCE();
    RD_A(d, 1);
    WAIT_LGKM0(); SCHED_FENCE();
    MFMA8(1, 0, b0);
    MFMA8(1, 1, b1);
  }
#undef STG_A
#undef STG_B
#undef RD_A
#undef RD_B
#undef MFMA8

  const int lr4 = lhi << 2;
#pragma unroll
  for (int m = 0; m < 8; ++m) {
#pragma unroll
    for (int n = 0; n < 4; ++n) {
      const int c_i = col0 + wc * 64 + n * 16 + ln15;
      const float bv = bias[c_i];
#pragma unroll
      for (int j = 0; j < 4; ++j) {
        const int r_i = row0 + wr * 128 + m * 16 + lr4 + j;
        const size_t idx = (size_t)r_i * N + c_i;
        float val = acc[m][n][j] + bv;
        if constexpr (EPI == 0) {
          ((bf16*)outp)[idx] = (bf16)val;
        } else if constexpr (EPI == 1) {
          ((bf16*)outp)[idx] = (bf16)(val > 0.f ? val + 1.f : __expf(val));
        } else if constexpr (EPI == 2) {
          ((float*)outp)[idx] = val + resid[idx];
        } else if constexpr (EPI == 3) {
          const float u  = 0.7978845608028654f * (val + 0.044715f * val * val * val);
          const float th = 1.f - 2.f / (__expf(2.f * u) + 1.f);
          ((bf16*)outp)[idx] = (bf16)(0.5f * val * (1.f + th));
        } else {
          if (c_i < 2048)
            ((bf16*)outp)[idx] = (bf16)(val > 0.f ? val + 1.f : __expf(val));
          else
            ((bf16*)outp)[idx] = (bf16)val;
        }
      }
    }
  }
}

// ---------------------------------------------------------------------------
// kv partials, roles swapped so output is kvT[e][d] = sum_t v[t,e]*kf[t,d].
// skf-buffer stages V, sv-buffer stages KF; ksum sums KF (the sv buffer).
// Inner loop vectorized: 2x bf16x8 LDS reads + shift-based bf16->f32.
// grid = 64 heads * 8 chunks of 512 tokens.
// ---------------------------------------------------------------------------
__global__ __launch_bounds__(256) void kv_part_kernel(
    const bf16* __restrict__ qkv, float* __restrict__ kv_part,
    float* __restrict__ ksum_part)
{
  const int bh = blockIdx.x >> 3, ch = blockIdx.x & 7;
  const int b = bh >> 4, h = bh & 15;
  const int tid = threadIdx.x;
  const int d = tid & 63, eg = tid >> 6;   // thread owns e in [eg*16, eg*16+16), col d
  const size_t grow0 = (size_t)b * 4096 + (size_t)ch * 512;
  const size_t vbase = 2048 + (size_t)h * 64;   // V columns
  __shared__ bf16 svv[8][64], skf[8][64];
  float accum[16];
#pragma unroll
  for (int i = 0; i < 16; ++i) accum[i] = 0.f;
  float ks = 0.f;
  const int tt = tid >> 5, cc = (tid & 31) << 1;
  for (int t0 = 0; t0 < 512; t0 += 8) {
    __syncthreads();
    const size_t base = (grow0 + t0 + tt) * 3072 + vbase + cc;
    *(uint32_t*)&svv[tt][cc] = *(const uint32_t*)(qkv + base);          // V
    *(uint32_t*)&skf[tt][cc] = *(const uint32_t*)(qkv + base - 1024);   // KF
    __syncthreads();
#pragma unroll
    for (int q = 0; q < 8; ++q) {
      const float kd = (float)skf[q][d];
      const uint32_t* u0 = (const uint32_t*)&svv[q][eg * 16];
#pragma unroll
      for (int i = 0; i < 8; ++i) {
        const uint32_t u = u0[i];
        const float lo = __uint_as_float(u << 16);
        const float hi = __uint_as_float(u & 0xffff0000u);
        accum[2 * i]     += lo * kd;
        accum[2 * i + 1] += hi * kd;
      }
    }
    if (tid < 64) {
#pragma unroll
      for (int q = 0; q < 8; ++q) ks += (float)skf[q][tid];
    }
  }
  // kvp[chunk][e][d]
  float* op = kv_part + (size_t)blockIdx.x * 4096 + (size_t)(eg * 16) * 64 + d;
#pragma unroll
  for (int ee = 0; ee < 16; ++ee) op[ee * 64] = accum[ee];
  if (tid < 64) ksum_part[(size_t)blockIdx.x * 64 + tid] = ks;
}

// ---------------------------------------------------------------------------
// reduce partials -> bf16 B-tile KB[80][64] per head:
// rows 0-63 = kvT[e][d], row 64 = ksum[d], rows 65-79 = 0.
// ---------------------------------------------------------------------------
__global__ __launch_bounds__(256) void kv_reduce(
    const float* __restrict__ kvp, const float* __restrict__ ksp,
    bf16* __restrict__ kb)
{
  const int bh = blockIdx.x;
  const int tid = threadIdx.x;
  bf16* KB = kb + (size_t)bh * 5120;
  for (int i = tid; i < 4096; i += 256) {
    float s = 0.f;
#pragma unroll
    for (int ch = 0; ch < 8; ++ch) s += kvp[((size_t)bh * 8 + ch) * 4096 + i];
    KB[i] = (bf16)s;
  }
  if (tid < 64) {
    float s = 0.f;
#pragma unroll
    for (int ch = 0; ch < 8; ++ch) s += ksp[((size_t)bh * 8 + ch) * 64 + tid];
    KB[4096 + tid] = (bf16)s;
  }
  for (int i = 4160 + tid; i < 5120; i += 256) KB[i] = (bf16)0.f;
}

// ---------------------------------------------------------------------------
// attn out via MFMA: per head, out[r][0..63] = qf[r]@kvT^T, out[r][64]=qf.ksum;
// write out[r][e] * 1/(out[r][64]+1e-6). A-frag = qf[row][d-contig] (global),
// B-frag = KB[outcol][d-contig] (global, L2/L3-hot). 256 thr = 4 waves, each
// 64 rows (4 m-tiles). grid = 64 bh * 16 rowblocks.
// ---------------------------------------------------------------------------
__global__ __launch_bounds__(256) void attn_mfma(
    const bf16* __restrict__ qkv, const bf16* __restrict__ kb,
    bf16* __restrict__ attn)
{
  const int bh = blockIdx.x >> 4, rb = blockIdx.x & 15;
  const int b = bh >> 4, h = bh & 15;
  const int tid = threadIdx.x, wid = tid >> 6, lane = tid & 63;
  const int ln15 = lane & 15, lhi = lane >> 4;
  const size_t row0 = (size_t)b * 4096 + rb * 256 + wid * 64;
  const bf16* KB = kb + (size_t)bh * 5120;

  bf16x8 bfr[5][2];
#pragma unroll
  for (int nb = 0; nb < 5; ++nb)
#pragma unroll
    for (int ks = 0; ks < 2; ++ks)
      bfr[nb][ks] = *(const bf16x8*)(KB + (nb * 16 + ln15) * 64 + ks * 32 + lhi * 8);

  for (int mt = 0; mt < 4; ++mt) {
    const bf16* ap = qkv + (row0 + mt * 16 + ln15) * 3072 + h * 64 + lhi * 8;
    const bf16x8 a0 = *(const bf16x8*)ap;
    const bf16x8 a1 = *(const bf16x8*)(ap + 32);
    f32x4 acc[5];
#pragma unroll
    for (int nb = 0; nb < 5; ++nb) {
      f32x4 z = {0.f, 0.f, 0.f, 0.f};
      z = __builtin_amdgcn_mfma_f32_16x16x32_bf16(a0, bfr[nb][0], z, 0, 0, 0);
      acc[nb] = __builtin_amdgcn_mfma_f32_16x16x32_bf16(a1, bfr[nb][1], z, 0, 0, 0);
    }
#pragma unroll
    for (int j = 0; j < 4; ++j) {
      const float ns = __shfl(acc[4][j], (lane & 48));   // col-0 lane of this row group
      const float inv = 1.f / (ns + 1e-6f);
      const size_t r = row0 + mt * 16 + (lhi << 2) + j;
#pragma unroll
      for (int nb = 0; nb < 4; ++nb)
        attn[r * 1024 + h * 64 + nb * 16 + ln15] = (bf16)(acc[nb][j] * inv);
    }
  }
}

// ---------------------------------------------------------------------------
// launch
// ---------------------------------------------------------------------------
extern "C" void kernel_launch(void* const* d_in, const int* in_sizes, int n_in,
                              void* d_out, int out_size, void* d_ws, size_t ws_size,
                              hipStream_t stream)
{
  const float* x    = (const float*)d_in[0];
  const float* ln1w = (const float*)d_in[1];
  const float* ln1b = (const float*)d_in[2];
  const float* qw   = (const float*)d_in[3];
  const float* qb   = (const float*)d_in[4];
  const float* kw   = (const float*)d_in[5];
  const float* kb_  = (const float*)d_in[6];
  const float* vw   = (const float*)d_in[7];
  const float* vb   = (const float*)d_in[8];
  const float* ow   = (const float*)d_in[9];
  const float* ob   = (const float*)d_in[10];
  const float* ln2w = (const float*)d_in[11];
  const float* ln2b = (const float*)d_in[12];
  const float* fcw  = (const float*)d_in[13];
  const float* fcb  = (const float*)d_in[14];
  const float* pjw  = (const float*)d_in[15];
  const float* pjb  = (const float*)d_in[16];
  float* out = (float*)d_out;
  char* ws = (char*)d_ws;

  constexpr size_t O_LNX  = 0;
  constexpr size_t O_QKV  = 33554432;
  constexpr size_t O_HMLP = 0;
  constexpr size_t O_KVP  = 134217728;
  constexpr size_t O_KSP  = 142606336;
  constexpr size_t O_KB   = 142737408;   // bf16 KB tiles, 64*5120*2 = 640KB
  constexpr size_t O_ATTN = 143802368;
  constexpr size_t O_LN2  = 177356800;
  constexpr size_t O_WQ   = 210911232;
  constexpr size_t O_WO   = 217202688;
  constexpr size_t O_WFC  = 219299840;
  constexpr size_t O_WPJ  = 227688448;

  bf16* lnx   = (bf16*)(ws + O_LNX);
  bf16* qkv   = (bf16*)(ws + O_QKV);
  bf16* hmlp  = (bf16*)(ws + O_HMLP);
  float* kvp  = (float*)(ws + O_KVP);
  float* qkvb = (float*)(ws + O_KVP);    // 12KB, dead before kv_part runs
  float* ksp  = (float*)(ws + O_KSP);
  bf16* kbt   = (bf16*)(ws + O_KB);
  bf16* attn  = (bf16*)(ws + O_ATTN);
  bf16* ln2h  = (bf16*)(ws + O_LN2);
  bf16* wqkvT = (bf16*)(ws + O_WQ);
  bf16* woT   = (bf16*)(ws + O_WO);
  bf16* wfcT  = (bf16*)(ws + O_WFC);
  bf16* wpjT  = (bf16*)(ws + O_WPJ);

  const dim3 tb(32, 8);
  transpose4<<<dim3(32, 32, 4), tb, 0, stream>>>(qw, kw, vw, ow, wqkvT, woT);
  transpose_cast<<<dim3(128, 32), tb, 0, stream>>>(fcw, wfcT, 1024, 4096);
  transpose_cast<<<dim3(32, 128), tb, 0, stream>>>(pjw, wpjT, 4096, 1024);
  pack3<<<12, 256, 0, stream>>>(qb, kb_, vb, qkvb);

  ln_row<<<16384, 256, 0, stream>>>(x, ln1w, ln1b, lnx);

  // fused q|k|v projection: [16384,1024] x [1024,3072]
  gemm256<4><<<768, 512, 0, stream>>>(lnx, wqkvT, qkvb, nullptr, qkv, 16384, 3072, 1024, 12);

  kv_part_kernel<<<512, 256, 0, stream>>>(qkv, kvp, ksp);
  kv_reduce<<<64, 256, 0, stream>>>(kvp, ksp, kbt);
  attn_mfma<<<1024, 256, 0, stream>>>(qkv, kbt, attn);

  // y1 = x + attn @ o_w + o_b   (f32 into d_out)
  gemm256<2><<<256, 512, 0, stream>>>(attn, woT, ob, x, out, 16384, 1024, 1024, 4);

  ln_row<<<16384, 256, 0, stream>>>(out, ln2w, ln2b, ln2h);

  gemm256<3><<<1024, 512, 0, stream>>>(ln2h, wfcT, fcb, nullptr, hmlp, 16384, 4096, 1024, 16);

  // out = y1 + h_mlp @ proj_w + proj_b  (in-place on d_out: read-before-write)
  gemm256<2><<<256, 512, 0, stream>>>(hmlp, wpjT, pjb, out, out, 16384, 1024, 4096, 4);
}